// Round 1
// baseline (277.182 us; speedup 1.0000x reference)
//
#include <hip/hip_runtime.h>
#include <hip/hip_bf16.h>
#include <math.h>

#define N_NODES 10000
#define N_EDGES 160000
#define IN_CH 128
#define EMB 64
#define HEADS 12
#define NEG_SLOPE 0.2f
#define NPB 8  // nodes per block in projection

// ---------- kernel 1: emb = relu(x @ We + be) ----------
__global__ __launch_bounds__(256) void embed_kernel(
    const float* __restrict__ x, const float* __restrict__ We,
    const float* __restrict__ be, float* __restrict__ emb, int nNodes) {
  int gid = blockIdx.x * 256 + threadIdx.x;
  int n = gid >> 6, j = gid & 63;
  if (n >= nNodes) return;
  float s = be[j];
  const float* xr = x + (long)n * IN_CH;
  #pragma unroll 8
  for (int k = 0; k < IN_CH; ++k) s += xr[k] * We[k * EMB + j];
  emb[gid] = fmaxf(s, 0.f);
}

// ---------- kernel 2: hh = emb @ W ; a_src/a_dst per-head logits ----------
__global__ __launch_bounds__(768) void project_kernel(
    const float* __restrict__ emb, const float* __restrict__ W,
    const float* __restrict__ att_src, const float* __restrict__ att_dst,
    float* __restrict__ hh, float* __restrict__ a_src, float* __restrict__ a_dst,
    int nNodes) {
  const int t = threadIdx.x;          // t = h*64 + d
  const int h = t >> 6, d = t & 63;
  const int n0 = blockIdx.x * NPB;
  __shared__ float emb_s[NPB][EMB];
  if (t < NPB * EMB) {
    int i = t >> 6, k = t & 63;
    int n = n0 + i;
    emb_s[i][k] = (n < nNodes) ? emb[(long)n * EMB + k] : 0.f;
  }
  __syncthreads();
  float val[NPB];
  #pragma unroll
  for (int i = 0; i < NPB; ++i) val[i] = 0.f;
  for (int k = 0; k < EMB; ++k) {
    float w = W[k * (HEADS * EMB) + t];
    #pragma unroll
    for (int i = 0; i < NPB; ++i) val[i] += emb_s[i][k] * w;
  }
  const float asv = att_src[t];  // att_src[h][d] flat == index t
  const float adv = att_dst[t];
  for (int i = 0; i < NPB; ++i) {
    int n = n0 + i;
    if (n >= nNodes) break;
    hh[(long)n * (HEADS * EMB) + t] = val[i];
    float rs = val[i] * asv;
    float rd = val[i] * adv;
    #pragma unroll
    for (int off = 32; off > 0; off >>= 1) {
      rs += __shfl_down(rs, off, 64);
      rd += __shfl_down(rd, off, 64);
    }
    if (d == 0) {
      a_src[n * HEADS + h] = rs;
      a_dst[n * HEADS + h] = rd;
    }
  }
}

// ---------- CSR build ----------
__global__ void zero_kernel(int* deg, int* cursor, int n) {
  int i = blockIdx.x * 256 + threadIdx.x;
  if (i < n) { deg[i] = 0; cursor[i] = 0; }
}

__global__ void count_kernel(const int* __restrict__ ei, int* __restrict__ deg,
                             int nE, int nN) {
  int e = blockIdx.x * 256 + threadIdx.x;
  if (e >= nE + nN) return;
  int dst = (e < nE) ? ei[nE + e] : (e - nE);  // self-loop for e >= nE
  atomicAdd(&deg[dst], 1);
}

__global__ __launch_bounds__(1024) void scan_kernel(
    const int* __restrict__ deg, int* __restrict__ row_start, int n) {
  __shared__ int tmp[1024];
  __shared__ int carry_s;
  const int tid = threadIdx.x;
  if (tid == 0) carry_s = 0;
  __syncthreads();
  for (int base = 0; base < n; base += 1024) {
    int i = base + tid;
    int v = (i < n) ? deg[i] : 0;
    tmp[tid] = v;
    __syncthreads();
    for (int off = 1; off < 1024; off <<= 1) {
      int t2 = (tid >= off) ? tmp[tid - off] : 0;
      __syncthreads();
      tmp[tid] += t2;
      __syncthreads();
    }
    if (i < n) row_start[i] = carry_s + tmp[tid] - v;  // exclusive
    __syncthreads();
    if (tid == 0) carry_s += tmp[1023];
    __syncthreads();
  }
  if (tid == 0) row_start[n] = carry_s;
}

__global__ void fill_kernel(const int* __restrict__ ei,
                            const int* __restrict__ row_start,
                            int* __restrict__ cursor, int* __restrict__ csr_src,
                            int nE, int nN) {
  int e = blockIdx.x * 256 + threadIdx.x;
  if (e >= nE + nN) return;
  int src, dst;
  if (e < nE) { src = ei[e]; dst = ei[nE + e]; }
  else        { src = e - nE; dst = e - nE; }
  int pos = atomicAdd(&cursor[dst], 1);
  csr_src[row_start[dst] + pos] = src;
}

// ---------- kernel 3: per-dst gather: softmax + weighted sum + epilogue ----------
__global__ __launch_bounds__(768) void gat_gather(
    const float* __restrict__ hh, const float* __restrict__ a_src,
    const float* __restrict__ a_dst, const float* __restrict__ emb,
    const float* __restrict__ bias, const int* __restrict__ row_start,
    const int* __restrict__ csr_src, float* __restrict__ out) {
  const int n = blockIdx.x;
  const int t = threadIdx.x;          // t = h*64 + d ; wave index == head
  const int h = t >> 6, d = t & 63;
  __shared__ int   srcs[64];
  __shared__ float wbuf[HEADS * 64];
  __shared__ float emax_s[HEADS];
  __shared__ float denom_s[HEADS];
  __shared__ float adst_s[HEADS];
  if (t < HEADS) {
    emax_s[t] = -1e30f;
    denom_s[t] = 0.f;
    adst_s[t] = a_dst[n * HEADS + t];
  }
  __syncthreads();
  const int e0 = row_start[n], e1 = row_start[n + 1];
  const int deg = e1 - e0;

  // pass 1: per-head segment max of leaky-relu logits
  for (int base = 0; base < deg; base += 64) {
    if (t < 64) {
      int i = base + t;
      srcs[t] = (i < deg) ? csr_src[e0 + i] : 0;
    }
    __syncthreads();
    int csize = min(64, deg - base);
    float lo = -1e30f;
    if (d < csize) {
      float e = a_src[srcs[d] * HEADS + h] + adst_s[h];
      lo = (e > 0.f) ? e : NEG_SLOPE * e;
    }
    #pragma unroll
    for (int off = 32; off > 0; off >>= 1)
      lo = fmaxf(lo, __shfl_down(lo, off, 64));
    if (d == 0) emax_s[h] = fmaxf(emax_s[h], lo);
    __syncthreads();
  }

  // pass 2: weights, denom, weighted gather-accumulate
  float acc = 0.f;
  for (int base = 0; base < deg; base += 64) {
    if (t < 64) {
      int i = base + t;
      srcs[t] = (i < deg) ? csr_src[e0 + i] : 0;
    }
    __syncthreads();
    int csize = min(64, deg - base);
    float w = 0.f;
    if (d < csize) {
      float e = a_src[srcs[d] * HEADS + h] + adst_s[h];
      e = (e > 0.f) ? e : NEG_SLOPE * e;
      w = expf(e - emax_s[h]);
    }
    wbuf[h * 64 + d] = w;
    float ws = w;
    #pragma unroll
    for (int off = 32; off > 0; off >>= 1) ws += __shfl_down(ws, off, 64);
    if (d == 0) denom_s[h] += ws;
    __syncthreads();
    for (int i = 0; i < csize; ++i) {
      acc += wbuf[h * 64 + i] * hh[(long)srcs[i] * (HEADS * EMB) + h * 64 + d];
    }
    __syncthreads();
  }

  // epilogue: normalize, head-mean, +bias, residual relu
  float y = acc / (denom_s[h] + 1e-16f);
  wbuf[t] = y;
  __syncthreads();
  if (t < 64) {
    float s = 0.f;
    #pragma unroll
    for (int hi = 0; hi < HEADS; ++hi) s += wbuf[hi * 64 + t];
    float yv = s * (1.f / HEADS) + bias[t];
    float r = emb[(long)n * EMB + t] + yv;
    out[(long)n * EMB + t] = fmaxf(r, 0.f);
  }
}

extern "C" void kernel_launch(void* const* d_in, const int* in_sizes, int n_in,
                              void* d_out, int out_size, void* d_ws, size_t ws_size,
                              hipStream_t stream) {
  const float* x       = (const float*)d_in[0];
  const int*   ei      = (const int*)  d_in[1];
  const float* We      = (const float*)d_in[2];
  const float* be      = (const float*)d_in[3];
  const float* W       = (const float*)d_in[4];
  const float* att_src = (const float*)d_in[5];
  const float* att_dst = (const float*)d_in[6];
  const float* bias    = (const float*)d_in[7];
  float* out = (float*)d_out;

  // workspace layout (all fp32/int32, 4B aligned)
  float* emb    = (float*)d_ws;            // 640000
  float* hh     = emb + N_NODES * EMB;     // 7,680,000
  float* a_src  = hh + (long)N_NODES * HEADS * EMB;   // 120000
  float* a_dst  = a_src + N_NODES * HEADS;            // 120000
  int*   deg    = (int*)(a_dst + N_NODES * HEADS);    // 10000
  int*   row_st = deg + N_NODES;                      // 10001
  int*   cursor = row_st + N_NODES + 1;               // 10000
  int*   csr    = cursor + N_NODES;                   // 170000

  const int nTot = N_EDGES + N_NODES;

  embed_kernel<<<(N_NODES * EMB + 255) / 256, 256, 0, stream>>>(x, We, be, emb, N_NODES);
  project_kernel<<<(N_NODES + NPB - 1) / NPB, 768, 0, stream>>>(
      emb, W, att_src, att_dst, hh, a_src, a_dst, N_NODES);
  zero_kernel<<<(N_NODES + 255) / 256, 256, 0, stream>>>(deg, cursor, N_NODES);
  count_kernel<<<(nTot + 255) / 256, 256, 0, stream>>>(ei, deg, N_EDGES, N_NODES);
  scan_kernel<<<1, 1024, 0, stream>>>(deg, row_st, N_NODES);
  fill_kernel<<<(nTot + 255) / 256, 256, 0, stream>>>(ei, row_st, cursor, csr, N_EDGES, N_NODES);
  gat_gather<<<N_NODES, 768, 0, stream>>>(hh, a_src, a_dst, emb, bias, row_st, csr, out);
}